// Round 18
// baseline (214.103 us; speedup 1.0000x reference)
//
#include <hip/hip_runtime.h>
#include <hip/hip_bf16.h>

#define NN 50000
#define NE 800000
#define HD 128
#define SCAN_CHUNK 1024
#define SCAN_BLOCKS ((NN + SCAN_CHUNK - 1) / SCAN_CHUNK)  // 49
#define NB_NODE 1024
#define EPB ((NE + NB_NODE - 1) / NB_NODE)                // 782 edges per node block
#define NB_SSUB 256
#define NB_SCAT (NB_SSUB * 8)                             // 2048 scatter blocks
#define EPC ((NE + NB_SSUB - 1) / NB_SSUB)                // 3125 edges per chunk
#define NPG (NN / 8)                                      // 6250 nodes per XCD group

typedef __attribute__((ext_vector_type(8))) short s16x8;
typedef __attribute__((ext_vector_type(4))) float f32x4;

static __device__ __forceinline__ unsigned short f2bf(float f) {
    unsigned int u = __float_as_uint(f);
    u = (u + 0x7FFFu + ((u >> 16) & 1u)) >> 16;
    return (unsigned short)u;
}
static __device__ __forceinline__ float bf2f(unsigned short h) {
    return __uint_as_float(((unsigned int)h) << 16);
}
static __device__ __forceinline__ unsigned int f2bf2(float lo, float hi) {
    __hip_bfloat162 h = __float22bfloat162_rn(make_float2(lo, hi));
    return *reinterpret_cast<unsigned int*>(&h);
}

// wave-level LDS fence: drain this wave's LDS ops, block compiler reordering.
#define WFENCE() do { asm volatile("s_waitcnt lgkmcnt(0)" ::: "memory"); \
                      __builtin_amdgcn_sched_barrier(0); } while (0)

// ---------------------------------------------------------------------------
// stage 1 (node + interleaved hist + aggH zero-fill):
//   block parity: half 0 -> xa, half 1 -> xb (+bc inline), column-swizzled.
// Swizzle: col c -> p(c) = (c&15)*8 + (c>>4); a lane's 16B chunk
// [r16*8..+8) holds cols {16t + r16} = edge kernel's MFMA C-fragment.
// ---------------------------------------------------------------------------
__global__ __launch_bounds__(256, 3) void node_kernel(
    const float* __restrict__ x, const float* __restrict__ mw1,
    const float* __restrict__ mb1, const float* __restrict__ pb2,
    const int* __restrict__ ei,
    unsigned short* __restrict__ xa, unsigned short* __restrict__ xb,
    float* __restrict__ aggH, int* __restrict__ cnt)
{
    __shared__ __align__(16) unsigned short sB[128 * 136];
    __shared__ __align__(16) unsigned short sSt[4][16 * 132];
    __shared__ int sIdx64;

    int bid = blockIdx.x;
    int tid = threadIdx.x;

    // zero aggH (grid-stride)
    {
        f32x4 z = {0.f, 0.f, 0.f, 0.f};
        const int total4 = NN * HD / 4;  // 1,600,000
        for (int i = bid * 256 + tid; i < total4; i += NB_NODE * 256)
            ((f32x4*)aggH)[i] = z;
    }
    if (tid == 0) {
        int z = 1;
        for (int k = 0; k < 16; ++k) if (ei[2 * k + 1] != 0) z = 0;
        sIdx64 = z;
    }
    int half = bid & 1;
    for (int idx = tid; idx < 128 * 128; idx += 256) {
        int c = idx & 127, k = idx >> 7;
        sB[c * 136 + k] = f2bf(mw1[(half * 128 + k) * 128 + c]);
    }
    __syncthreads();

    // ---- hist role (interleaved): fire-and-forget atomics overlap the GEMM
    {
        int he0 = bid * EPB;
        int he1 = he0 + EPB; if (he1 > NE) he1 = NE;
        if (sIdx64) {
            for (int e = he0 + tid; e < he1; e += 256)
                atomicAdd(&cnt[ei[2 * NE + 2 * e]], 1);
        } else {
            for (int e = he0 + tid; e < he1; e += 256)
                atomicAdd(&cnt[ei[NE + e]], 1);
        }
    }

    int lane = tid & 63, wv = tid >> 6;
    int r16 = lane & 15, g4 = lane >> 4;
    unsigned short* st = sSt[wv];
    unsigned short* dst = half ? xb : xa;

    float bcr[8];
    #pragma unroll
    for (int tc = 0; tc < 8; ++tc) bcr[tc] = 0.f;
    if (half) {
        #pragma unroll
        for (int tc = 0; tc < 8; ++tc) bcr[tc] = mb1[tc * 16 + r16];
        for (int i = 0; i < 32; ++i) {
            float pv = pb2[i];
            #pragma unroll
            for (int tc = 0; tc < 8; ++tc)
                bcr[tc] = fmaf(pv, mw1[(256 + i) * 128 + tc * 16 + r16], bcr[tc]);
        }
    }

    const int NT = NN / 16;  // 3125
    const int nb = NB_NODE >> 1;
    const int nbid = bid >> 1;

    for (int t = nbid * 4 + wv; t < NT; t += nb * 4) {
        int r0 = t * 16;
        int row = r0 + r16;
        s16x8 a[4];
        #pragma unroll
        for (int ks = 0; ks < 4; ++ks) {
            const float* p = &x[(size_t)row * HD + ks * 32 + g4 * 8];
            float4 v0 = *(const float4*)p;
            float4 v1 = *(const float4*)(p + 4);
            union { s16x8 v; unsigned int u[4]; } av;
            av.u[0] = f2bf2(v0.x, v0.y); av.u[1] = f2bf2(v0.z, v0.w);
            av.u[2] = f2bf2(v1.x, v1.y); av.u[3] = f2bf2(v1.z, v1.w);
            a[ks] = av.v;
        }
        float hold[4];
        #pragma unroll
        for (int tc = 0; tc < 8; ++tc) {
            int col = tc * 16 + r16;
            float bv = bcr[tc];
            f32x4 acc = {bv, bv, bv, bv};
            #pragma unroll
            for (int ks = 0; ks < 4; ++ks) {
                s16x8 b = *(const s16x8*)&sB[col * 136 + ks * 32 + g4 * 8];
                acc = __builtin_amdgcn_mfma_f32_16x16x32_bf16(a[ks], b, acc, 0, 0, 0);
            }
            if ((tc & 1) == 0) {
                #pragma unroll
                for (int j = 0; j < 4; ++j) hold[j] = acc[j];
            } else {
                #pragma unroll
                for (int j = 0; j < 4; ++j)
                    *(unsigned int*)&st[(g4 * 4 + j) * 132 + r16 * 8 + (tc - 1)] =
                        f2bf2(hold[j], acc[j]);
            }
        }
        WFENCE();
        #pragma unroll
        for (int i = 0; i < 4; ++i) {
            int idx = i * 512 + lane * 8;
            int rr = idx >> 7, cc = idx & 127;
            *(s16x8*)&dst[(size_t)(r0 + rr) * HD + cc] = *(const s16x8*)&st[rr * 132 + cc];
        }
        WFENCE();
    }
}

// ---------------------------------------------------------------------------
// scan1: per-chunk exclusive scan -> cursor, chunk totals -> bsum
// ---------------------------------------------------------------------------
__global__ void scan1_kernel(const int* __restrict__ cnt, int* __restrict__ cursor,
                             int* __restrict__ bsum)
{
    __shared__ int tot[256];
    int b = blockIdx.x, t = threadIdx.x;
    int i0 = b * SCAN_CHUNK + t * 4;
    int v[4];
    #pragma unroll
    for (int k = 0; k < 4; ++k) v[k] = (i0 + k < NN) ? cnt[i0 + k] : 0;
    tot[t] = v[0] + v[1] + v[2] + v[3];
    __syncthreads();
    if (t == 0) {
        int run = 0;
        for (int i = 0; i < 256; ++i) { int x = tot[i]; tot[i] = run; run += x; }
        bsum[b] = run;
    }
    __syncthreads();
    int p = tot[t];
    #pragma unroll
    for (int k = 0; k < 4; ++k) {
        if (i0 + k < NN) cursor[i0 + k] = p;
        p += v[k];
    }
}

// scan3: add cross-chunk carry; ALSO fill sC (sorted segment-id array):
// sC[start[c] .. start[c]+deg(c)) = c  (coalesced-ish run writes).
__global__ void scan3_kernel(int* __restrict__ cursor, const int* __restrict__ bsum,
                             const int* __restrict__ cnt, int* __restrict__ sC)
{
    __shared__ int sCarry;
    int b = blockIdx.x, t = threadIdx.x;
    if (t == 0) {
        int run = 0;
        for (int i = 0; i < b; ++i) run += bsum[i];
        sCarry = run;
    }
    __syncthreads();
    int carry = sCarry;
    int i0 = b * SCAN_CHUNK + t * 4;
    #pragma unroll
    for (int k = 0; k < 4; ++k) {
        int i = i0 + k;
        if (i < NN) {
            int s = cursor[i] + carry;
            cursor[i] = s;
            int n = cnt[i];
            for (int j = 0; j < n; ++j) sC[s + j] = i;
        }
    }
}

// ---------------------------------------------------------------------------
// scatter (XCD-LOCAL) + prep (fused): group g = bid & 7 handles only
// destinations c in [g*NPG, (g+1)*NPG) -> every sR line / cursor counter is
// written by one XCD (no cross-XCD partial-line evictions).
// ---------------------------------------------------------------------------
__global__ void scatterprep_kernel(
    const int* __restrict__ ei, int* __restrict__ cursor, int* __restrict__ sR,
    const float* __restrict__ pw2, const float* __restrict__ mw1,
    const float* __restrict__ mw2, const float* __restrict__ mb2,
    const float* __restrict__ uw1,
    float* __restrict__ Wpc, float* __restrict__ W3, float* __restrict__ b3)
{
    __shared__ int sIdx64;
    int bid = blockIdx.x, tid = threadIdx.x;

    if (bid >= NB_SCAT) {
        int rb = bid - NB_SCAT;  // 0..64
        if (rb == 64) {
            for (int idx = tid; idx < 32 * 128; idx += 256) {
                int j = idx >> 7, k = idx & 127;
                float s = 0.f;
                #pragma unroll 8
                for (int i = 0; i < 32; ++i) s += pw2[j * 32 + i] * mw1[(256 + i) * 128 + k];
                Wpc[idx] = s;
            }
            return;
        }
        int idx = rb * 256 + tid;   // 0..16383
        {
            int k = idx >> 7, j = idx & 127;
            float s = 0.f;
            #pragma unroll 4
            for (int c = 0; c < 128; ++c)
                s += mw2[k * 128 + c] * uw1[(128 + c) * 128 + j];
            W3[idx] = s;
        }
        if (rb == 0 && tid < 128) {
            int j = tid;
            float s = 0.f;
            #pragma unroll 4
            for (int c = 0; c < 128; ++c)
                s += mb2[c] * uw1[(128 + c) * 128 + j];
            b3[j] = s;
        }
        return;
    }

    if (tid == 0) {
        int z = 1;
        for (int k = 0; k < 16; ++k) if (ei[2 * k + 1] != 0) z = 0;
        sIdx64 = z;
    }
    __syncthreads();

    int g = bid & 7;            // XCD group (dispatch round-robin heuristic)
    int sub = bid >> 3;         // chunk id 0..NB_SSUB-1
    int clo = g * NPG;
    int chi = (g == 7) ? NN : clo + NPG;
    int e0 = sub * EPC;
    int e1 = e0 + EPC; if (e1 > NE) e1 = NE;

    if (sIdx64) {
        for (int e = e0 + tid; e < e1; e += 256) {
            int c = ei[2 * NE + 2 * e];
            if (c >= clo && c < chi) {
                int r = ei[2 * e];
                int p = atomicAdd(&cursor[c], 1);
                sR[p] = r;
            }
        }
    } else {
        for (int e = e0 + tid; e < e1; e += 256) {
            int c = ei[NE + e];
            if (c >= clo && c < chi) {
                int r = ei[e];
                int p = atomicAdd(&cursor[c], 1);
                sR[p] = r;
            }
        }
    }
}

// ---------------------------------------------------------------------------
// stage 2 (edges, SORTED by col): swizzled xa/xb gathers deliver the MFMA
// C-fragment in registers. NEW: 2-deep gather pipeline — double-buffered
// ga/gb (even/odd tiles), meta rotated 4-5 tiles ahead (clamped indices;
// only segred guarded). Gathers get ~2 full tile bodies of latency cover.
// ---------------------------------------------------------------------------
__global__ __launch_bounds__(256, 3) void edge_kernel(
    const float* __restrict__ pos,
    const int* __restrict__ sR, const int* __restrict__ sC,
    const float* __restrict__ pw1, const float* __restrict__ pb1,
    const unsigned short* __restrict__ xa, const unsigned short* __restrict__ xb,
    const float* __restrict__ Wpc,
    float* __restrict__ aggH)
{
    __shared__ __align__(16) unsigned short sT[4][16 * 136];  // relu(h1), swizzled cols

    int tid = threadIdx.x;
    int lane = tid & 63, wv = tid >> 6;
    int r16 = lane & 15, g4 = lane >> 4;
    unsigned short* stg = sT[wv];

    s16x8 wr[8];
    #pragma unroll
    for (int tc = 0; tc < 8; ++tc) {
        s16x8 w;
        #pragma unroll
        for (int i = 0; i < 8; ++i)
            w[i] = (short)f2bf(Wpc[(g4 * 8 + i) * 128 + tc * 16 + r16]);
        wr[tc] = w;
    }
    float pw10[8], pw11[8], pw12[8], pb1r[8];
    #pragma unroll
    for (int i = 0; i < 8; ++i) {
        int k = g4 * 8 + i;
        pw10[i] = pw1[k]; pw11[i] = pw1[32 + k]; pw12[i] = pw1[64 + k];
        pb1r[i] = pb1[k];
    }

    const int NW = gridDim.x * 4;
    const int NT = NE / 16;  // 50000
    int gw = blockIdx.x * 4 + wv;
    if (gw >= NT) return;

#define LOAD_META(M, TT)                                                    \
    { int tt_ = (TT) < NT ? (TT) : NT - 1;                                  \
      M.x = sR[tt_ * 16 + r16]; M.y = sC[tt_ * 16 + r16]; }

#define POSDIFF(D0, D1, D2, M)                                              \
    D0 = pos[M.x * 3 + 0] - pos[M.y * 3 + 0];                               \
    D1 = pos[M.x * 3 + 1] - pos[M.y * 3 + 1];                               \
    D2 = pos[M.x * 3 + 2] - pos[M.y * 3 + 2];

#define GATHER_TILE(GA, GB, M)                                              \
    _Pragma("unroll")                                                       \
    for (int j = 0; j < 4; ++j) {                                           \
        int gx = __shfl(M.x, g4 * 4 + j, 64);                               \
        int gy = __shfl(M.y, g4 * 4 + j, 64);                               \
        GA[j] = *(const s16x8*)&xa[(size_t)gx * HD + r16 * 8];              \
        GB[j] = *(const s16x8*)&xb[(size_t)gy * HD + r16 * 8];              \
    }

#define GEMM1_TILE(GA, GB, D0, D1, D2)                                      \
    {                                                                       \
        union { s16x8 v; unsigned int u[4]; } apf;                          \
        _Pragma("unroll")                                                   \
        for (int i2 = 0; i2 < 4; ++i2) {                                    \
            int i = 2 * i2;                                                 \
            float v0_ = fmaf(D0, pw10[i], fmaf(D1, pw11[i], fmaf(D2, pw12[i], pb1r[i])));          \
            float v1_ = fmaf(D0, pw10[i+1], fmaf(D1, pw11[i+1], fmaf(D2, pw12[i+1], pb1r[i+1])));  \
            apf.u[i2] = f2bf2(fmaxf(v0_, 0.f), fmaxf(v1_, 0.f));            \
        }                                                                   \
        float hold[4];                                                      \
        _Pragma("unroll")                                                   \
        for (int tc = 0; tc < 8; ++tc) {                                    \
            f32x4 acc;                                                      \
            _Pragma("unroll")                                               \
            for (int j = 0; j < 4; ++j)                                     \
                acc[j] = bf2f((unsigned short)GA[j][tc]) + bf2f((unsigned short)GB[j][tc]);        \
            acc = __builtin_amdgcn_mfma_f32_16x16x32_bf16(apf.v, wr[tc], acc, 0, 0, 0);            \
            if ((tc & 1) == 0) {                                            \
                _Pragma("unroll")                                           \
                for (int j = 0; j < 4; ++j) hold[j] = fmaxf(acc[j], 0.f);   \
            } else {                                                        \
                _Pragma("unroll")                                           \
                for (int j = 0; j < 4; ++j)                                 \
                    *(unsigned int*)&stg[(g4 * 4 + j) * 136 + r16 * 8 + (tc - 1)] =                \
                        f2bf2(hold[j], fmaxf(acc[j], 0.f));                 \
            }                                                               \
        }                                                                   \
    }

#define SEGRED_TILE(TT)                                                     \
    {                                                                       \
        int tb_ = __builtin_amdgcn_readfirstlane(TT);                       \
        const int* __restrict__ scp = sC + tb_ * 16;                        \
        int p0 = (lane & 15) * 8 + (lane >> 4);                             \
        int p1 = p0 + 4;                                                    \
        int cur = scp[0];                                                   \
        float run0 = bf2f(stg[p0]);                                         \
        float run1 = bf2f(stg[p1]);                                         \
        _Pragma("unroll")                                                   \
        for (int e = 1; e < 16; ++e) {                                      \
            int c = scp[e];                                                 \
            float v0_ = bf2f(stg[e * 136 + p0]);                            \
            float v1_ = bf2f(stg[e * 136 + p1]);                            \
            if (c != cur) {                                                 \
                unsafeAtomicAdd(&aggH[(size_t)cur * HD + lane], run0);      \
                unsafeAtomicAdd(&aggH[(size_t)cur * HD + lane + 64], run1); \
                cur = c; run0 = v0_; run1 = v1_;                            \
            } else { run0 += v0_; run1 += v1_; }                            \
        }                                                                   \
        unsafeAtomicAdd(&aggH[(size_t)cur * HD + lane], run0);              \
        unsafeAtomicAdd(&aggH[(size_t)cur * HD + lane + 64], run1);         \
    }

    // prologue: meta 0..+3, gathers + pos diffs for first two tiles
    int2 m0, m1, m2, m3;
    LOAD_META(m0, gw);
    LOAD_META(m1, gw + NW);
    LOAD_META(m2, gw + 2 * NW);
    LOAD_META(m3, gw + 3 * NW);
    s16x8 ga0[4], gb0[4], ga1[4], gb1[4];
    GATHER_TILE(ga0, gb0, m0);
    GATHER_TILE(ga1, gb1, m1);
    float dpA0, dpA1, dpA2, dpB0, dpB1, dpB2;
    POSDIFF(dpA0, dpA1, dpA2, m0);
    POSDIFF(dpB0, dpB1, dpB2, m1);

    for (int t = gw; t < NT; t += 2 * NW) {
        // ===== even tile t (data: ga0/gb0) =====
        GEMM1_TILE(ga0, gb0, dpA0, dpA1, dpA2);
        WFENCE();
        GATHER_TILE(ga0, gb0, m2);              // for t+2NW (2 tiles of cover)
        int2 m4; LOAD_META(m4, t + 4 * NW);
        POSDIFF(dpA0, dpA1, dpA2, m2);
        SEGRED_TILE(t);
        WFENCE();

        // ===== odd tile t+NW (data: ga1/gb1) =====
        GEMM1_TILE(ga1, gb1, dpB0, dpB1, dpB2); // harmless if t+NW >= NT
        WFENCE();
        GATHER_TILE(ga1, gb1, m3);              // for t+3NW
        int2 m5; LOAD_META(m5, t + 5 * NW);
        POSDIFF(dpB0, dpB1, dpB2, m3);
        if (t + NW < NT) {
            SEGRED_TILE(t + NW);
            WFENCE();
        }
        m2 = m4; m3 = m5;
    }

#undef LOAD_META
#undef POSDIFF
#undef GATHER_TILE
#undef GEMM1_TILE
#undef SEGRED_TILE
}

// ---------------------------------------------------------------------------
// stage 3 (FUSED): t = relu(x@uw1a + aggH@W3 + deg*b3 + ub1); out = t@uw2+ub2
// 768 threads, 12 waves/CU (LDS 156.7 KB of 160), 1 block/CU.
// ---------------------------------------------------------------------------
__global__ __launch_bounds__(768, 1) void upd_kernel(
    const float* __restrict__ x, const float* __restrict__ aggH,
    const int* __restrict__ cnt,
    const float* __restrict__ uw1, const float* __restrict__ ub1,
    const float* __restrict__ W3, const float* __restrict__ b3,
    const float* __restrict__ uw2, const float* __restrict__ ub2,
    float* __restrict__ out)
{
    __shared__ __align__(16) unsigned short sB1a[128 * 136];   // uw1a [c][k<128]
    __shared__ __align__(16) unsigned short sW3l[128 * 136];   // W3   [c][k<128]
    __shared__ __align__(16) unsigned short sB2[128 * 136];    // uw2  [c][k<128]
    __shared__ __align__(16) unsigned short sSt[12][16 * 136]; // per-wave t tile

    int tid = threadIdx.x;
    for (int idx = tid; idx < 128 * 128; idx += 768) {
        int c = idx & 127, k = idx >> 7;
        sB1a[c * 136 + k] = f2bf(uw1[k * 128 + c]);
        sW3l[c * 136 + k] = f2bf(W3[k * 128 + c]);
        sB2[c * 136 + k]  = f2bf(uw2[k * 128 + c]);
    }
    __syncthreads();

    int lane = tid & 63, wv = tid >> 6;   // wv in 0..11
    int r16 = lane & 15, g4 = lane >> 4;
    unsigned short* st = sSt[wv];
    float ub1r[8], ub2r[8], b3r[8];
    #pragma unroll
    for (int tc = 0; tc < 8; ++tc) {
        ub1r[tc] = ub1[tc * 16 + r16];
        ub2r[tc] = ub2[tc * 16 + r16];
        b3r[tc]  = b3[tc * 16 + r16];
    }

    const int NT = NN / 16;  // 3125
    for (int t = blockIdx.x * 12 + wv; t < NT; t += gridDim.x * 12) {
        int r0 = t * 16;
        int row = r0 + r16;
        s16x8 a[8];
        #pragma unroll
        for (int ks = 0; ks < 8; ++ks) {
            const float* p = (ks < 4) ? &x[(size_t)row * HD + ks * 32 + g4 * 8]
                                      : &aggH[(size_t)row * HD + (ks - 4) * 32 + g4 * 8];
            float4 v0 = *(const float4*)p;
            float4 v1 = *(const float4*)(p + 4);
            union { s16x8 v; unsigned int u[4]; } av;
            av.u[0] = f2bf2(v0.x, v0.y); av.u[1] = f2bf2(v0.z, v0.w);
            av.u[2] = f2bf2(v1.x, v1.y); av.u[3] = f2bf2(v1.z, v1.w);
            a[ks] = av.v;
        }
        float cn[4];
        #pragma unroll
        for (int j = 0; j < 4; ++j) cn[j] = (float)cnt[r0 + g4 * 4 + j];

        #pragma unroll
        for (int tc = 0; tc < 8; ++tc) {
            int col = tc * 16 + r16;
            f32x4 acc;
            #pragma unroll
            for (int j = 0; j < 4; ++j) acc[j] = ub1r[tc] + cn[j] * b3r[tc];
            #pragma unroll
            for (int ks = 0; ks < 4; ++ks) {
                s16x8 b = *(const s16x8*)&sB1a[col * 136 + ks * 32 + g4 * 8];
                acc = __builtin_amdgcn_mfma_f32_16x16x32_bf16(a[ks], b, acc, 0, 0, 0);
            }
            #pragma unroll
            for (int ks = 4; ks < 8; ++ks) {
                s16x8 b = *(const s16x8*)&sW3l[col * 136 + (ks - 4) * 32 + g4 * 8];
                acc = __builtin_amdgcn_mfma_f32_16x16x32_bf16(a[ks], b, acc, 0, 0, 0);
            }
            #pragma unroll
            for (int j = 0; j < 4; ++j)
                st[(g4 * 4 + j) * 136 + col] = f2bf(fmaxf(acc[j], 0.f));
        }
        WFENCE();
        s16x8 a2[4];
        #pragma unroll
        for (int ks = 0; ks < 4; ++ks)
            a2[ks] = *(const s16x8*)&st[r16 * 136 + ks * 32 + g4 * 8];
        WFENCE();
        #pragma unroll
        for (int tc = 0; tc < 8; ++tc) {
            int col = tc * 16 + r16;
            float bv = ub2r[tc];
            f32x4 acc = {bv, bv, bv, bv};
            #pragma unroll
            for (int ks = 0; ks < 4; ++ks) {
                s16x8 b = *(const s16x8*)&sB2[col * 136 + ks * 32 + g4 * 8];
                acc = __builtin_amdgcn_mfma_f32_16x16x32_bf16(a2[ks], b, acc, 0, 0, 0);
            }
            #pragma unroll
            for (int j = 0; j < 4; ++j)
                out[(size_t)(r0 + g4 * 4 + j) * HD + col] = acc[j];
        }
    }
}

// ---------------------------------------------------------------------------
extern "C" void kernel_launch(void* const* d_in, const int* in_sizes, int n_in,
                              void* d_out, int out_size, void* d_ws, size_t ws_size,
                              hipStream_t stream)
{
    const float* x   = (const float*)d_in[0];
    const float* pos = (const float*)d_in[1];
    const int*   ei  = (const int*)d_in[2];
    const float* pw1 = (const float*)d_in[3];
    const float* pb1 = (const float*)d_in[4];
    const float* pw2 = (const float*)d_in[5];
    const float* pb2 = (const float*)d_in[6];
    const float* mw1 = (const float*)d_in[7];
    const float* mb1 = (const float*)d_in[8];
    const float* mw2 = (const float*)d_in[9];
    const float* mb2 = (const float*)d_in[10];
    const float* uw1 = (const float*)d_in[11];
    const float* ub1 = (const float*)d_in[12];
    const float* uw2 = (const float*)d_in[13];
    const float* ub2 = (const float*)d_in[14];
    float* out = (float*)d_out;

    char* ws = (char*)d_ws;
    float*          aggH   = (float*)(ws);                      // 25,600,000 B
    unsigned short* xa     = (unsigned short*)(ws + 25600000);  // 12,800,000 B
    unsigned short* xb     = (unsigned short*)(ws + 38400000);  // 12,800,000 B
    float*          Wpc    = (float*)(ws + 51200000);           // 16,384 B
    int*            cnt    = (int*)(ws + 51216896);             // 200,704 B
    int*            cursor = (int*)(ws + 51417600);             // 200,704 B
    int*            bsum   = (int*)(ws + 51618304);             // 256 B
    int*            sR     = (int*)(ws + 51618560);             // 3,200,000 B
    int*            sC     = (int*)(ws + 54818560);             // 3,200,000 B
    float*          W3     = (float*)(ws + 58018560);           // 65,536 B
    float*          b3     = (float*)(ws + 58084096);           // 512 B

    hipMemsetAsync(cnt, 0, NN * sizeof(int), stream);
    node_kernel<<<NB_NODE, 256, 0, stream>>>(x, mw1, mb1, pb2, ei, xa, xb, aggH, cnt);
    scan1_kernel<<<SCAN_BLOCKS, 256, 0, stream>>>(cnt, cursor, bsum);
    scan3_kernel<<<SCAN_BLOCKS, 256, 0, stream>>>(cursor, bsum, cnt, sC);
    scatterprep_kernel<<<NB_SCAT + 65, 256, 0, stream>>>(
        ei, cursor, sR, pw2, mw1, mw2, mb2, uw1, Wpc, W3, b3);
    edge_kernel<<<768, 256, 0, stream>>>(pos, sR, sC, pw1, pb1, xa, xb, Wpc, aggH);
    upd_kernel<<<256, 768, 0, stream>>>(x, aggH, cnt, uw1, ub1, W3, b3, uw2, ub2, out);
}

// Round 19
// 211.875 us; speedup vs baseline: 1.0105x; 1.0105x over previous
//
#include <hip/hip_runtime.h>
#include <hip/hip_bf16.h>

#define NN 50000
#define NE 800000
#define HD 128
#define SCAN_CHUNK 1024
#define SCAN_BLOCKS ((NN + SCAN_CHUNK - 1) / SCAN_CHUNK)  // 49
#define NB_NODE 1024
#define EPB ((NE + NB_NODE - 1) / NB_NODE)                // 782 edges per node block
#define NB_SSUB 256
#define NB_SCAT (NB_SSUB * 8)                             // 2048 scatter blocks
#define EPC ((NE + NB_SSUB - 1) / NB_SSUB)                // 3125 edges per chunk
#define NPG (NN / 8)                                      // 6250 nodes per XCD group

typedef __attribute__((ext_vector_type(8))) short s16x8;
typedef __attribute__((ext_vector_type(4))) float f32x4;

static __device__ __forceinline__ unsigned short f2bf(float f) {
    unsigned int u = __float_as_uint(f);
    u = (u + 0x7FFFu + ((u >> 16) & 1u)) >> 16;
    return (unsigned short)u;
}
static __device__ __forceinline__ float bf2f(unsigned short h) {
    return __uint_as_float(((unsigned int)h) << 16);
}
static __device__ __forceinline__ unsigned int f2bf2(float lo, float hi) {
    __hip_bfloat162 h = __float22bfloat162_rn(make_float2(lo, hi));
    return *reinterpret_cast<unsigned int*>(&h);
}

// wave-level LDS fence: drain this wave's LDS ops, block compiler reordering.
#define WFENCE() do { asm volatile("s_waitcnt lgkmcnt(0)" ::: "memory"); \
                      __builtin_amdgcn_sched_barrier(0); } while (0)

// ---------------------------------------------------------------------------
// stage 1 (node + interleaved hist + aggH zero-fill):
//   block parity: half 0 -> xa, half 1 -> xb (+bc inline), column-swizzled.
// Swizzle: col c -> p(c) = (c&15)*8 + (c>>4); a lane's 16B chunk
// [r16*8..+8) holds cols {16t + r16} = edge kernel's MFMA C-fragment.
// ---------------------------------------------------------------------------
__global__ __launch_bounds__(256, 3) void node_kernel(
    const float* __restrict__ x, const float* __restrict__ mw1,
    const float* __restrict__ mb1, const float* __restrict__ pb2,
    const int* __restrict__ ei,
    unsigned short* __restrict__ xa, unsigned short* __restrict__ xb,
    float* __restrict__ aggH, int* __restrict__ cnt)
{
    __shared__ __align__(16) unsigned short sB[128 * 136];
    __shared__ __align__(16) unsigned short sSt[4][16 * 132];
    __shared__ int sIdx64;

    int bid = blockIdx.x;
    int tid = threadIdx.x;

    // zero aggH (grid-stride)
    {
        f32x4 z = {0.f, 0.f, 0.f, 0.f};
        const int total4 = NN * HD / 4;  // 1,600,000
        for (int i = bid * 256 + tid; i < total4; i += NB_NODE * 256)
            ((f32x4*)aggH)[i] = z;
    }
    if (tid == 0) {
        int z = 1;
        for (int k = 0; k < 16; ++k) if (ei[2 * k + 1] != 0) z = 0;
        sIdx64 = z;
    }
    int half = bid & 1;
    for (int idx = tid; idx < 128 * 128; idx += 256) {
        int c = idx & 127, k = idx >> 7;
        sB[c * 136 + k] = f2bf(mw1[(half * 128 + k) * 128 + c]);
    }
    __syncthreads();

    // ---- hist role (interleaved): fire-and-forget atomics overlap the GEMM
    {
        int he0 = bid * EPB;
        int he1 = he0 + EPB; if (he1 > NE) he1 = NE;
        if (sIdx64) {
            for (int e = he0 + tid; e < he1; e += 256)
                atomicAdd(&cnt[ei[2 * NE + 2 * e]], 1);
        } else {
            for (int e = he0 + tid; e < he1; e += 256)
                atomicAdd(&cnt[ei[NE + e]], 1);
        }
    }

    int lane = tid & 63, wv = tid >> 6;
    int r16 = lane & 15, g4 = lane >> 4;
    unsigned short* st = sSt[wv];
    unsigned short* dst = half ? xb : xa;

    float bcr[8];
    #pragma unroll
    for (int tc = 0; tc < 8; ++tc) bcr[tc] = 0.f;
    if (half) {
        #pragma unroll
        for (int tc = 0; tc < 8; ++tc) bcr[tc] = mb1[tc * 16 + r16];
        for (int i = 0; i < 32; ++i) {
            float pv = pb2[i];
            #pragma unroll
            for (int tc = 0; tc < 8; ++tc)
                bcr[tc] = fmaf(pv, mw1[(256 + i) * 128 + tc * 16 + r16], bcr[tc]);
        }
    }

    const int NT = NN / 16;  // 3125
    const int nb = NB_NODE >> 1;
    const int nbid = bid >> 1;

    for (int t = nbid * 4 + wv; t < NT; t += nb * 4) {
        int r0 = t * 16;
        int row = r0 + r16;
        s16x8 a[4];
        #pragma unroll
        for (int ks = 0; ks < 4; ++ks) {
            const float* p = &x[(size_t)row * HD + ks * 32 + g4 * 8];
            float4 v0 = *(const float4*)p;
            float4 v1 = *(const float4*)(p + 4);
            union { s16x8 v; unsigned int u[4]; } av;
            av.u[0] = f2bf2(v0.x, v0.y); av.u[1] = f2bf2(v0.z, v0.w);
            av.u[2] = f2bf2(v1.x, v1.y); av.u[3] = f2bf2(v1.z, v1.w);
            a[ks] = av.v;
        }
        float hold[4];
        #pragma unroll
        for (int tc = 0; tc < 8; ++tc) {
            int col = tc * 16 + r16;
            float bv = bcr[tc];
            f32x4 acc = {bv, bv, bv, bv};
            #pragma unroll
            for (int ks = 0; ks < 4; ++ks) {
                s16x8 b = *(const s16x8*)&sB[col * 136 + ks * 32 + g4 * 8];
                acc = __builtin_amdgcn_mfma_f32_16x16x32_bf16(a[ks], b, acc, 0, 0, 0);
            }
            if ((tc & 1) == 0) {
                #pragma unroll
                for (int j = 0; j < 4; ++j) hold[j] = acc[j];
            } else {
                #pragma unroll
                for (int j = 0; j < 4; ++j)
                    *(unsigned int*)&st[(g4 * 4 + j) * 132 + r16 * 8 + (tc - 1)] =
                        f2bf2(hold[j], acc[j]);
            }
        }
        WFENCE();
        #pragma unroll
        for (int i = 0; i < 4; ++i) {
            int idx = i * 512 + lane * 8;
            int rr = idx >> 7, cc = idx & 127;
            *(s16x8*)&dst[(size_t)(r0 + rr) * HD + cc] = *(const s16x8*)&st[rr * 132 + cc];
        }
        WFENCE();
    }
}

// ---------------------------------------------------------------------------
// scan1: per-chunk exclusive scan -> cursor, chunk totals -> bsum
// ---------------------------------------------------------------------------
__global__ void scan1_kernel(const int* __restrict__ cnt, int* __restrict__ cursor,
                             int* __restrict__ bsum)
{
    __shared__ int tot[256];
    int b = blockIdx.x, t = threadIdx.x;
    int i0 = b * SCAN_CHUNK + t * 4;
    int v[4];
    #pragma unroll
    for (int k = 0; k < 4; ++k) v[k] = (i0 + k < NN) ? cnt[i0 + k] : 0;
    tot[t] = v[0] + v[1] + v[2] + v[3];
    __syncthreads();
    if (t == 0) {
        int run = 0;
        for (int i = 0; i < 256; ++i) { int x = tot[i]; tot[i] = run; run += x; }
        bsum[b] = run;
    }
    __syncthreads();
    int p = tot[t];
    #pragma unroll
    for (int k = 0; k < 4; ++k) {
        if (i0 + k < NN) cursor[i0 + k] = p;
        p += v[k];
    }
}

// scan3: add cross-chunk carry; ALSO fill sC (sorted segment-id array):
// sC[start[c] .. start[c]+deg(c)) = c  (coalesced-ish run writes).
__global__ void scan3_kernel(int* __restrict__ cursor, const int* __restrict__ bsum,
                             const int* __restrict__ cnt, int* __restrict__ sC)
{
    __shared__ int sCarry;
    int b = blockIdx.x, t = threadIdx.x;
    if (t == 0) {
        int run = 0;
        for (int i = 0; i < b; ++i) run += bsum[i];
        sCarry = run;
    }
    __syncthreads();
    int carry = sCarry;
    int i0 = b * SCAN_CHUNK + t * 4;
    #pragma unroll
    for (int k = 0; k < 4; ++k) {
        int i = i0 + k;
        if (i < NN) {
            int s = cursor[i] + carry;
            cursor[i] = s;
            int n = cnt[i];
            for (int j = 0; j < n; ++j) sC[s + j] = i;
        }
    }
}

// ---------------------------------------------------------------------------
// scatter (XCD-LOCAL) + prep (fused): group g = bid & 7 handles only
// destinations c in [g*NPG, (g+1)*NPG) -> every sR line / cursor counter is
// written by one XCD (no cross-XCD partial-line evictions).
// ---------------------------------------------------------------------------
__global__ void scatterprep_kernel(
    const int* __restrict__ ei, int* __restrict__ cursor, int* __restrict__ sR,
    const float* __restrict__ pw2, const float* __restrict__ mw1,
    const float* __restrict__ mw2, const float* __restrict__ mb2,
    const float* __restrict__ uw1,
    float* __restrict__ Wpc, float* __restrict__ W3, float* __restrict__ b3)
{
    __shared__ int sIdx64;
    int bid = blockIdx.x, tid = threadIdx.x;

    if (bid >= NB_SCAT) {
        int rb = bid - NB_SCAT;  // 0..64
        if (rb == 64) {
            for (int idx = tid; idx < 32 * 128; idx += 256) {
                int j = idx >> 7, k = idx & 127;
                float s = 0.f;
                #pragma unroll 8
                for (int i = 0; i < 32; ++i) s += pw2[j * 32 + i] * mw1[(256 + i) * 128 + k];
                Wpc[idx] = s;
            }
            return;
        }
        int idx = rb * 256 + tid;   // 0..16383
        {
            int k = idx >> 7, j = idx & 127;
            float s = 0.f;
            #pragma unroll 4
            for (int c = 0; c < 128; ++c)
                s += mw2[k * 128 + c] * uw1[(128 + c) * 128 + j];
            W3[idx] = s;
        }
        if (rb == 0 && tid < 128) {
            int j = tid;
            float s = 0.f;
            #pragma unroll 4
            for (int c = 0; c < 128; ++c)
                s += mb2[c] * uw1[(128 + c) * 128 + j];
            b3[j] = s;
        }
        return;
    }

    if (tid == 0) {
        int z = 1;
        for (int k = 0; k < 16; ++k) if (ei[2 * k + 1] != 0) z = 0;
        sIdx64 = z;
    }
    __syncthreads();

    int g = bid & 7;            // XCD group (dispatch round-robin heuristic)
    int sub = bid >> 3;         // chunk id 0..NB_SSUB-1
    int clo = g * NPG;
    int chi = (g == 7) ? NN : clo + NPG;
    int e0 = sub * EPC;
    int e1 = e0 + EPC; if (e1 > NE) e1 = NE;

    if (sIdx64) {
        for (int e = e0 + tid; e < e1; e += 256) {
            int c = ei[2 * NE + 2 * e];
            if (c >= clo && c < chi) {
                int r = ei[2 * e];
                int p = atomicAdd(&cursor[c], 1);
                sR[p] = r;
            }
        }
    } else {
        for (int e = e0 + tid; e < e1; e += 256) {
            int c = ei[NE + e];
            if (c >= clo && c < chi) {
                int r = ei[e];
                int p = atomicAdd(&cursor[c], 1);
                sR[p] = r;
            }
        }
    }
}

// ---------------------------------------------------------------------------
// stage 2 (edges, SORTED by col): swizzled xa/xb -> gathers deliver the MFMA
// C-fragment directly in registers. Segment ids come from sC via wave-uniform
// SCALAR loads (readfirstlane) -> no sECs LDS at all. lb(256,3), grid 768.
// ---------------------------------------------------------------------------
__global__ __launch_bounds__(256, 3) void edge_kernel(
    const float* __restrict__ pos,
    const int* __restrict__ sR, const int* __restrict__ sC,
    const float* __restrict__ pw1, const float* __restrict__ pb1,
    const unsigned short* __restrict__ xa, const unsigned short* __restrict__ xb,
    const float* __restrict__ Wpc,
    float* __restrict__ aggH)
{
    __shared__ __align__(16) unsigned short sT[4][16 * 136];  // relu(h1), swizzled cols

    int tid = threadIdx.x;
    int lane = tid & 63, wv = tid >> 6;
    int r16 = lane & 15, g4 = lane >> 4;
    unsigned short* stg = sT[wv];

    s16x8 wr[8];
    #pragma unroll
    for (int tc = 0; tc < 8; ++tc) {
        s16x8 w;
        #pragma unroll
        for (int i = 0; i < 8; ++i)
            w[i] = (short)f2bf(Wpc[(g4 * 8 + i) * 128 + tc * 16 + r16]);
        wr[tc] = w;
    }
    float pw10[8], pw11[8], pw12[8], pb1r[8];
    #pragma unroll
    for (int i = 0; i < 8; ++i) {
        int k = g4 * 8 + i;
        pw10[i] = pw1[k]; pw11[i] = pw1[32 + k]; pw12[i] = pw1[64 + k];
        pb1r[i] = pb1[k];
    }

    const int NW = gridDim.x * 4;
    const int NT = NE / 16;  // 50000
    int gw = blockIdx.x * 4 + wv;
    if (gw >= NT) return;

    int2 rc, rcN;
    rc.x = sR[gw * 16 + r16];
    rc.y = sC[gw * 16 + r16];
    rcN = rc;
    if (gw + NW < NT) {
        rcN.x = sR[(gw + NW) * 16 + r16];
        rcN.y = sC[(gw + NW) * 16 + r16];
    }
    float dp0 = pos[rc.x * 3 + 0] - pos[rc.y * 3 + 0];
    float dp1 = pos[rc.x * 3 + 1] - pos[rc.y * 3 + 1];
    float dp2 = pos[rc.x * 3 + 2] - pos[rc.y * 3 + 2];
    s16x8 ga[4], gb[4];
    #pragma unroll
    for (int j = 0; j < 4; ++j) {
        int gx = __shfl(rc.x, g4 * 4 + j, 64);
        int gy = __shfl(rc.y, g4 * 4 + j, 64);
        ga[j] = *(const s16x8*)&xa[(size_t)gx * HD + r16 * 8];
        gb[j] = *(const s16x8*)&xb[(size_t)gy * HD + r16 * 8];
    }

    for (int t = gw; t < NT; t += NW) {
        bool hn  = (t + NW) < NT;
        bool hn2 = (t + 2 * NW) < NT;

        // ---- 1. pos-MLP layer1 in A-frag layout
        union { s16x8 v; unsigned int u[4]; } apf;
        #pragma unroll
        for (int i2 = 0; i2 < 4; ++i2) {
            int i = 2 * i2;
            float v0 = fmaf(dp0, pw10[i], fmaf(dp1, pw11[i], fmaf(dp2, pw12[i], pb1r[i])));
            float v1 = fmaf(dp0, pw10[i+1], fmaf(dp1, pw11[i+1], fmaf(dp2, pw12[i+1], pb1r[i+1])));
            apf.u[i2] = f2bf2(fmaxf(v0, 0.f), fmaxf(v1, 0.f));
        }

        // ---- 2. GEMM1: acc init = xa[row]+xb[col] from gather regs; relu -> stg
        float hold[4];
        #pragma unroll
        for (int tc = 0; tc < 8; ++tc) {
            f32x4 acc;
            #pragma unroll
            for (int j = 0; j < 4; ++j)
                acc[j] = bf2f((unsigned short)ga[j][tc]) + bf2f((unsigned short)gb[j][tc]);
            acc = __builtin_amdgcn_mfma_f32_16x16x32_bf16(apf.v, wr[tc], acc, 0, 0, 0);
            if ((tc & 1) == 0) {
                #pragma unroll
                for (int j = 0; j < 4; ++j) hold[j] = fmaxf(acc[j], 0.f);
            } else {
                #pragma unroll
                for (int j = 0; j < 4; ++j)
                    *(unsigned int*)&stg[(g4 * 4 + j) * 136 + r16 * 8 + (tc - 1)] =
                        f2bf2(hold[j], fmaxf(acc[j], 0.f));
            }
        }
        WFENCE();

        // ---- 3. next-tile gathers (covered by segred + next apf)
        if (hn) {
            #pragma unroll
            for (int j = 0; j < 4; ++j) {
                int gx = __shfl(rcN.x, g4 * 4 + j, 64);
                int gy = __shfl(rcN.y, g4 * 4 + j, 64);
                ga[j] = *(const s16x8*)&xa[(size_t)gx * HD + r16 * 8];
                gb[j] = *(const s16x8*)&xb[(size_t)gy * HD + r16 * 8];
            }
        }

        // ---- 4. meta for t+2, pos diffs for t+1
        int2 rcN2 = rcN;
        if (hn2) {
            int i2x = (t + 2 * NW) * 16 + r16;
            rcN2.x = sR[i2x];
            rcN2.y = sC[i2x];
        }
        float dp0N = 0.f, dp1N = 0.f, dp2N = 0.f;
        if (hn) {
            dp0N = pos[rcN.x * 3 + 0] - pos[rcN.y * 3 + 0];
            dp1N = pos[rcN.x * 3 + 1] - pos[rcN.y * 3 + 1];
            dp2N = pos[rcN.x * 3 + 2] - pos[rcN.y * 3 + 2];
        }

        // ---- 5. segmented sum over sorted cols; segment ids via SCALAR loads
        {
            int tb = __builtin_amdgcn_readfirstlane(t);
            const int* __restrict__ scp = sC + tb * 16;  // wave-uniform -> SMEM
            int p0 = (lane & 15) * 8 + (lane >> 4);  // swizzled pos of col lane
            int p1 = p0 + 4;                          // swizzled pos of col lane+64
            int cur = scp[0];
            float run0 = bf2f(stg[p0]);
            float run1 = bf2f(stg[p1]);
            #pragma unroll
            for (int e = 1; e < 16; ++e) {
                int c = scp[e];
                float v0 = bf2f(stg[e * 136 + p0]);
                float v1 = bf2f(stg[e * 136 + p1]);
                if (c != cur) {  // wave-uniform
                    unsafeAtomicAdd(&aggH[(size_t)cur * HD + lane], run0);
                    unsafeAtomicAdd(&aggH[(size_t)cur * HD + lane + 64], run1);
                    cur = c; run0 = v0; run1 = v1;
                } else { run0 += v0; run1 += v1; }
            }
            unsafeAtomicAdd(&aggH[(size_t)cur * HD + lane], run0);
            unsafeAtomicAdd(&aggH[(size_t)cur * HD + lane + 64], run1);
        }
        WFENCE();

        rc = rcN; rcN = rcN2; dp0 = dp0N; dp1 = dp1N; dp2 = dp2N;
    }
}

// ---------------------------------------------------------------------------
// stage 3 (FUSED): t = relu(x@uw1a + aggH@W3 + deg*b3 + ub1); out = t@uw2+ub2
// 768 threads, 12 waves/CU (LDS 156.7 KB of 160), 1 block/CU.
// ---------------------------------------------------------------------------
__global__ __launch_bounds__(768, 1) void upd_kernel(
    const float* __restrict__ x, const float* __restrict__ aggH,
    const int* __restrict__ cnt,
    const float* __restrict__ uw1, const float* __restrict__ ub1,
    const float* __restrict__ W3, const float* __restrict__ b3,
    const float* __restrict__ uw2, const float* __restrict__ ub2,
    float* __restrict__ out)
{
    __shared__ __align__(16) unsigned short sB1a[128 * 136];   // uw1a [c][k<128]
    __shared__ __align__(16) unsigned short sW3l[128 * 136];   // W3   [c][k<128]
    __shared__ __align__(16) unsigned short sB2[128 * 136];    // uw2  [c][k<128]
    __shared__ __align__(16) unsigned short sSt[12][16 * 136]; // per-wave t tile

    int tid = threadIdx.x;
    for (int idx = tid; idx < 128 * 128; idx += 768) {
        int c = idx & 127, k = idx >> 7;
        sB1a[c * 136 + k] = f2bf(uw1[k * 128 + c]);
        sW3l[c * 136 + k] = f2bf(W3[k * 128 + c]);
        sB2[c * 136 + k]  = f2bf(uw2[k * 128 + c]);
    }
    __syncthreads();

    int lane = tid & 63, wv = tid >> 6;   // wv in 0..11
    int r16 = lane & 15, g4 = lane >> 4;
    unsigned short* st = sSt[wv];
    float ub1r[8], ub2r[8], b3r[8];
    #pragma unroll
    for (int tc = 0; tc < 8; ++tc) {
        ub1r[tc] = ub1[tc * 16 + r16];
        ub2r[tc] = ub2[tc * 16 + r16];
        b3r[tc]  = b3[tc * 16 + r16];
    }

    const int NT = NN / 16;  // 3125
    for (int t = blockIdx.x * 12 + wv; t < NT; t += gridDim.x * 12) {
        int r0 = t * 16;
        int row = r0 + r16;
        s16x8 a[8];
        #pragma unroll
        for (int ks = 0; ks < 8; ++ks) {
            const float* p = (ks < 4) ? &x[(size_t)row * HD + ks * 32 + g4 * 8]
                                      : &aggH[(size_t)row * HD + (ks - 4) * 32 + g4 * 8];
            float4 v0 = *(const float4*)p;
            float4 v1 = *(const float4*)(p + 4);
            union { s16x8 v; unsigned int u[4]; } av;
            av.u[0] = f2bf2(v0.x, v0.y); av.u[1] = f2bf2(v0.z, v0.w);
            av.u[2] = f2bf2(v1.x, v1.y); av.u[3] = f2bf2(v1.z, v1.w);
            a[ks] = av.v;
        }
        float cn[4];
        #pragma unroll
        for (int j = 0; j < 4; ++j) cn[j] = (float)cnt[r0 + g4 * 4 + j];

        #pragma unroll
        for (int tc = 0; tc < 8; ++tc) {
            int col = tc * 16 + r16;
            f32x4 acc;
            #pragma unroll
            for (int j = 0; j < 4; ++j) acc[j] = ub1r[tc] + cn[j] * b3r[tc];
            #pragma unroll
            for (int ks = 0; ks < 4; ++ks) {
                s16x8 b = *(const s16x8*)&sB1a[col * 136 + ks * 32 + g4 * 8];
                acc = __builtin_amdgcn_mfma_f32_16x16x32_bf16(a[ks], b, acc, 0, 0, 0);
            }
            #pragma unroll
            for (int ks = 4; ks < 8; ++ks) {
                s16x8 b = *(const s16x8*)&sW3l[col * 136 + (ks - 4) * 32 + g4 * 8];
                acc = __builtin_amdgcn_mfma_f32_16x16x32_bf16(a[ks], b, acc, 0, 0, 0);
            }
            #pragma unroll
            for (int j = 0; j < 4; ++j)
                st[(g4 * 4 + j) * 136 + col] = f2bf(fmaxf(acc[j], 0.f));
        }
        WFENCE();
        s16x8 a2[4];
        #pragma unroll
        for (int ks = 0; ks < 4; ++ks)
            a2[ks] = *(const s16x8*)&st[r16 * 136 + ks * 32 + g4 * 8];
        WFENCE();
        #pragma unroll
        for (int tc = 0; tc < 8; ++tc) {
            int col = tc * 16 + r16;
            float bv = ub2r[tc];
            f32x4 acc = {bv, bv, bv, bv};
            #pragma unroll
            for (int ks = 0; ks < 4; ++ks) {
                s16x8 b = *(const s16x8*)&sB2[col * 136 + ks * 32 + g4 * 8];
                acc = __builtin_amdgcn_mfma_f32_16x16x32_bf16(a2[ks], b, acc, 0, 0, 0);
            }
            #pragma unroll
            for (int j = 0; j < 4; ++j)
                out[(size_t)(r0 + g4 * 4 + j) * HD + col] = acc[j];
        }
    }
}

// ---------------------------------------------------------------------------
extern "C" void kernel_launch(void* const* d_in, const int* in_sizes, int n_in,
                              void* d_out, int out_size, void* d_ws, size_t ws_size,
                              hipStream_t stream)
{
    const float* x   = (const float*)d_in[0];
    const float* pos = (const float*)d_in[1];
    const int*   ei  = (const int*)d_in[2];
    const float* pw1 = (const float*)d_in[3];
    const float* pb1 = (const float*)d_in[4];
    const float* pw2 = (const float*)d_in[5];
    const float* pb2 = (const float*)d_in[6];
    const float* mw1 = (const float*)d_in[7];
    const float* mb1 = (const float*)d_in[8];
    const float* mw2 = (const float*)d_in[9];
    const float* mb2 = (const float*)d_in[10];
    const float* uw1 = (const float*)d_in[11];
    const float* ub1 = (const float*)d_in[12];
    const float* uw2 = (const float*)d_in[13];
    const float* ub2 = (const float*)d_in[14];
    float* out = (float*)d_out;

    char* ws = (char*)d_ws;
    float*          aggH   = (float*)(ws);                      // 25,600,000 B
    unsigned short* xa     = (unsigned short*)(ws + 25600000);  // 12,800,000 B
    unsigned short* xb     = (unsigned short*)(ws + 38400000);  // 12,800,000 B
    float*          Wpc    = (float*)(ws + 51200000);           // 16,384 B
    int*            cnt    = (int*)(ws + 51216896);             // 200,704 B
    int*            cursor = (int*)(ws + 51417600);             // 200,704 B
    int*            bsum   = (int*)(ws + 51618304);             // 256 B
    int*            sR     = (int*)(ws + 51618560);             // 3,200,000 B
    int*            sC     = (int*)(ws + 54818560);             // 3,200,000 B
    float*          W3     = (float*)(ws + 58018560);           // 65,536 B
    float*          b3     = (float*)(ws + 58084096);           // 512 B

    hipMemsetAsync(cnt, 0, NN * sizeof(int), stream);
    node_kernel<<<NB_NODE, 256, 0, stream>>>(x, mw1, mb1, pb2, ei, xa, xb, aggH, cnt);
    scan1_kernel<<<SCAN_BLOCKS, 256, 0, stream>>>(cnt, cursor, bsum);
    scan3_kernel<<<SCAN_BLOCKS, 256, 0, stream>>>(cursor, bsum, cnt, sC);
    scatterprep_kernel<<<NB_SCAT + 65, 256, 0, stream>>>(
        ei, cursor, sR, pw2, mw1, mw2, mb2, uw1, Wpc, W3, b3);
    edge_kernel<<<768, 256, 0, stream>>>(pos, sR, sC, pw1, pb1, xa, xb, Wpc, aggH);
    upd_kernel<<<256, 768, 0, stream>>>(x, aggH, cnt, uw1, ub1, W3, b3, uw2, ub2, out);
}